// Round 2
// baseline (367.487 us; speedup 1.0000x reference)
//
#include <hip/hip_runtime.h>
#include <math.h>

typedef short  short8  __attribute__((ext_vector_type(8)));
typedef short  short4v __attribute__((ext_vector_type(4)));
typedef float  f32x4   __attribute__((ext_vector_type(4)));

#define BATCH 32768
#define DIN   256
#define DOUT  512
#define BM    128
#define BN    128
#define BK    64

// round-to-nearest-even fp32 -> bf16 bits
__device__ __forceinline__ short f2bf(float v) {
    unsigned u = __float_as_uint(v);
    u += 0x7fffu + ((u >> 16) & 1u);
    return (short)(u >> 16);
}

// Stage a 128x64 fp32 tile from global into LDS as bf16.
// LDS layout: row-major [128][64] shorts, 16B granules XOR-swizzled by row:
// g' = g ^ (row & 7). Frag-read pattern (16 rows, same granule) then spans all
// 8 granule positions twice -> 2-way alias = free (m136).
// All 8 global loads issued before any convert/ds_write to maximize
// outstanding VMEM (latency hiding at low occupancy).
__device__ __forceinline__ void stage64(const float* __restrict__ g, int ld,
                                        int row0, int k0, int tid, short* s) {
    float4 v[8];
#pragma unroll
    for (int i = 0; i < 8; i++) {
        int p  = tid + i * 256;      // float4 index in 128x16-float4 tile
        int r  = p >> 4;
        int c4 = p & 15;
        v[i] = *(const float4*)(g + (size_t)(row0 + r) * ld + k0 + c4 * 4);
    }
#pragma unroll
    for (int i = 0; i < 8; i++) {
        int p   = tid + i * 256;
        int r   = p >> 4;
        int c4  = p & 15;
        int gr  = (c4 >> 1) ^ (r & 7);
        int addr = r * 64 + gr * 8 + (c4 & 1) * 4;
        *(short4v*)(s + addr) = (short4v){f2bf(v[i].x), f2bf(v[i].y),
                                          f2bf(v[i].z), f2bf(v[i].w)};
    }
}

__global__ __launch_bounds__(256, 2) void spike_rnn_lif_kernel(
    const float* __restrict__ X,    // input_spike [B, 256]
    const float* __restrict__ MEM,  // [B, 512]
    const float* __restrict__ SPK,  // [B, 512]
    const float* __restrict__ Wd,   // [512, 256]
    const float* __restrict__ bd,   // [512]
    const float* __restrict__ Wr,   // [512, 512]
    const float* __restrict__ br,   // [512]
    const float* __restrict__ tau,  // [512]
    float* __restrict__ out)        // [2, B, 512]: mem_new then spike_new
{
    __shared__ short sA[BM * BK];   // 16 KB
    __shared__ short sB[BN * BK];   // 16 KB
    __shared__ int   s_flag;

    const int tid  = threadIdx.x;
    const int lane = tid & 63;
    const int w    = tid >> 6;
    const int wm   = w & 1;
    const int wn   = w >> 1;
    const int bn   = blockIdx.x;    // 0..3
    const int bm   = blockIdx.y;    // 0..255
    const int m0   = bm * BM;
    const int n0   = bn * BN;
    const int col  = lane & 15;
    const int quad = lane >> 4;

    // ---- SNN sparsity scan: is this block's spike m-tile all zero? ----
    // 128x512 floats = 64 float4 per thread. Event-driven skip of the
    // recurrent GEMM (and the epilogue soft-reset read) when no spikes.
    if (tid == 0) s_flag = 0;
    __syncthreads();
    {
        unsigned acc_bits = 0;
#pragma unroll 8
        for (int i = 0; i < 64; i++) {
            int p = tid + i * 256;               // float4 idx, 128 per row
            const float4 v = *(const float4*)(SPK + (size_t)(m0 + (p >> 7)) * DOUT
                                              + (size_t)(p & 127) * 4);
            acc_bits |= __float_as_uint(v.x) | __float_as_uint(v.y)
                      | __float_as_uint(v.z) | __float_as_uint(v.w);
        }
        if (acc_bits) s_flag = 1;
    }
    __syncthreads();
    const bool has_spk = (s_flag != 0);

    f32x4 acc[4][4];
#pragma unroll
    for (int i = 0; i < 4; i++)
#pragma unroll
        for (int j = 0; j < 4; j++)
            acc[i][j] = (f32x4){0.f, 0.f, 0.f, 0.f};

    // ---- Phase 1: dense GEMM, K=256, plain bf16 (error 6x under threshold) --
    for (int kb = 0; kb < DIN; kb += BK) {
        stage64(X,  DIN, m0, kb, tid, sA);
        stage64(Wd, DIN, n0, kb, tid, sB);
        __syncthreads();
#pragma unroll
        for (int ks = 0; ks < 2; ks++) {        // two 16x16x32 k-steps per tile
            short8 ah[4], bh[4];
#pragma unroll
            for (int t = 0; t < 4; t++) {
                int ra = wm * 64 + t * 16 + col;
                ah[t] = *(const short8*)(sA + ra * 64 + ((ks * 4 + quad) ^ (ra & 7)) * 8);
                int rb = wn * 64 + t * 16 + col;
                bh[t] = *(const short8*)(sB + rb * 64 + ((ks * 4 + quad) ^ (rb & 7)) * 8);
            }
#pragma unroll
            for (int i = 0; i < 4; i++)
#pragma unroll
                for (int j = 0; j < 4; j++)
                    acc[i][j] = __builtin_amdgcn_mfma_f32_16x16x32_bf16(ah[i], bh[j], acc[i][j], 0, 0, 0);
        }
        __syncthreads();
    }

    // ---- Phase 2: recurrent GEMM, K=512 — only if spikes exist ----
    if (has_spk) {
        for (int kb = 0; kb < DOUT; kb += BK) {
            stage64(SPK, DOUT, m0, kb, tid, sA);
            stage64(Wr,  DOUT, n0, kb, tid, sB);
            __syncthreads();
#pragma unroll
            for (int ks = 0; ks < 2; ks++) {
                short8 ah[4], bh[4];
#pragma unroll
                for (int t = 0; t < 4; t++) {
                    int ra = wm * 64 + t * 16 + col;
                    ah[t] = *(const short8*)(sA + ra * 64 + ((ks * 4 + quad) ^ (ra & 7)) * 8);
                    int rb = wn * 64 + t * 16 + col;
                    bh[t] = *(const short8*)(sB + rb * 64 + ((ks * 4 + quad) ^ (rb & 7)) * 8);
                }
#pragma unroll
                for (int i = 0; i < 4; i++)
#pragma unroll
                    for (int j = 0; j < 4; j++)
                        acc[i][j] = __builtin_amdgcn_mfma_f32_16x16x32_bf16(ah[i], bh[j], acc[i][j], 0, 0, 0);
            }
            __syncthreads();
        }
    }

    // ---- Epilogue: LIF dynamics, fused ----
    // C/D layout (m89/m91-verified): col = lane&15, row = (lane>>4)*4 + reg
#pragma unroll
    for (int j = 0; j < 4; j++) {
        int n = n0 + wn * 64 + j * 16 + col;
        float alpha = expf(-1.0f / tau[n]);
        float bsum  = bd[n] + br[n];            // b_rec added unconditionally
#pragma unroll
        for (int i = 0; i < 4; i++) {
            int mbase = m0 + wm * 64 + i * 16 + quad * 4;
#pragma unroll
            for (int rr = 0; rr < 4; rr++) {
                size_t idx = (size_t)(mbase + rr) * DOUT + n;
                float d       = acc[i][j][rr] + bsum;
                float spk     = has_spk ? SPK[idx] : 0.0f;
                float mem_new = MEM[idx] * alpha + (1.0f - alpha) * d - 0.5f * spk;
                out[idx] = mem_new;
                out[(size_t)BATCH * DOUT + idx] = (mem_new - 0.5f > 0.0f) ? 1.0f : 0.0f;
            }
        }
    }
}

extern "C" void kernel_launch(void* const* d_in, const int* in_sizes, int n_in,
                              void* d_out, int out_size, void* d_ws, size_t ws_size,
                              hipStream_t stream) {
    const float* X   = (const float*)d_in[0];
    const float* MEM = (const float*)d_in[1];
    const float* SPK = (const float*)d_in[2];
    const float* Wd  = (const float*)d_in[3];
    const float* bd  = (const float*)d_in[4];
    const float* Wr  = (const float*)d_in[5];
    const float* br  = (const float*)d_in[6];
    const float* tau = (const float*)d_in[7];

    dim3 grid(DOUT / BN, BATCH / BM);   // (4, 256)
    spike_rnn_lif_kernel<<<grid, 256, 0, stream>>>(X, MEM, SPK, Wd, bd, Wr, br, tau,
                                                   (float*)d_out);
}

// Round 3
// 341.240 us; speedup vs baseline: 1.0769x; 1.0769x over previous
//
#include <hip/hip_runtime.h>
#include <math.h>

typedef short  short8  __attribute__((ext_vector_type(8)));
typedef short  short4v __attribute__((ext_vector_type(4)));
typedef float  f32x4   __attribute__((ext_vector_type(4)));

#define BATCH 32768
#define DIN   256
#define DOUT  512
#define BM    128
#define BN    64
#define BK    64

// round-to-nearest-even fp32 -> bf16 bits
__device__ __forceinline__ short f2bf(float v) {
    unsigned u = __float_as_uint(v);
    u += 0x7fffu + ((u >> 16) & 1u);
    return (short)(u >> 16);
}

// ---------------------------------------------------------------------------
// Pre-kernel: per-128-row-tile spike presence flags. Reads SPK exactly once
// (64 MB, streaming, 256 blocks x 1024 threads), writes flags[256] into d_ws.
// Removes the r2 mistake of every GEMM block rescanning 256 KB of SPK.
// ---------------------------------------------------------------------------
__global__ __launch_bounds__(1024) void spike_flag_kernel(
    const float* __restrict__ SPK, int* __restrict__ flags)
{
    __shared__ int s_any;
    if (threadIdx.x == 0) s_any = 0;
    __syncthreads();
    const float4* p = (const float4*)(SPK + (size_t)blockIdx.x * BM * DOUT);
    unsigned bits = 0;
#pragma unroll
    for (int i = 0; i < 16; i++) {           // 128*512/4 = 16384 float4 / 1024 thr
        float4 v = p[threadIdx.x + i * 1024];
        bits |= __float_as_uint(v.x) | __float_as_uint(v.y)
              | __float_as_uint(v.z) | __float_as_uint(v.w);
    }
    if (bits) s_any = 1;                     // benign race: same value
    __syncthreads();
    if (threadIdx.x == 0) flags[blockIdx.x] = s_any;
}

// Stage a 128x64 fp32 tile -> LDS bf16, row-major [128][64] shorts,
// 16B granules XOR-swizzled: g' = g ^ (row & 7) (2-way alias = free, m136).
__device__ __forceinline__ void stageA(const float* __restrict__ g, int ld,
                                       int row0, int k0, int tid, short* s) {
    float4 v[8];
#pragma unroll
    for (int i = 0; i < 8; i++) {
        int p  = tid + i * 256;
        v[i] = *(const float4*)(g + (size_t)(row0 + (p >> 4)) * ld + k0 + (p & 15) * 4);
    }
#pragma unroll
    for (int i = 0; i < 8; i++) {
        int p   = tid + i * 256;
        int r   = p >> 4;
        int c4  = p & 15;
        int addr = r * 64 + (((c4 >> 1) ^ (r & 7)) * 8) + (c4 & 1) * 4;
        *(short4v*)(s + addr) = (short4v){f2bf(v[i].x), f2bf(v[i].y),
                                          f2bf(v[i].z), f2bf(v[i].w)};
    }
}

// Stage a 64x64 fp32 tile -> LDS bf16, same layout.
__device__ __forceinline__ void stageB(const float* __restrict__ g, int ld,
                                       int row0, int k0, int tid, short* s) {
    float4 v[4];
#pragma unroll
    for (int i = 0; i < 4; i++) {
        int p  = tid + i * 256;
        v[i] = *(const float4*)(g + (size_t)(row0 + (p >> 4)) * ld + k0 + (p & 15) * 4);
    }
#pragma unroll
    for (int i = 0; i < 4; i++) {
        int p   = tid + i * 256;
        int r   = p >> 4;
        int c4  = p & 15;
        int addr = r * 64 + (((c4 >> 1) ^ (r & 7)) * 8) + (c4 & 1) * 4;
        *(short4v*)(s + addr) = (short4v){f2bf(v[i].x), f2bf(v[i].y),
                                          f2bf(v[i].z), f2bf(v[i].w)};
    }
}

// ---------------------------------------------------------------------------
// Main kernel. Block tile 128(m) x 64(n), BK=64, 4 waves as 2x2 of 64x32
// wave tiles -> acc = 4x2 mfma tiles = 32 fp32/lane (32 AGPR). Total unified
// regs ~128 -> 4 waves/SIMD -> 4 blocks/CU (LDS 24KB). r2's 64-AGPR acc put
// us at 192 regs -> 2 blocks/CU -> the measured 22% occupancy.
// ---------------------------------------------------------------------------
__global__ __launch_bounds__(256, 4) void spike_rnn_lif_kernel(
    const float* __restrict__ X,    // [B, 256]
    const float* __restrict__ MEM,  // [B, 512]
    const float* __restrict__ SPK,  // [B, 512]
    const float* __restrict__ Wd,   // [512, 256]
    const float* __restrict__ bd,   // [512]
    const float* __restrict__ Wr,   // [512, 512]
    const float* __restrict__ br,   // [512]
    const float* __restrict__ tau,  // [512]
    const int*   __restrict__ flags,// [256] per-m-tile spike presence
    float* __restrict__ out)        // [2, B, 512]
{
    __shared__ short sA[BM * BK];   // 16 KB
    __shared__ short sB[BN * BK];   // 8 KB

    const int tid  = threadIdx.x;
    const int lane = tid & 63;
    const int w    = tid >> 6;
    const int wm   = w & 1;         // m half (64 rows)
    const int wn   = w >> 1;        // n half (32 cols)
    const int bn   = blockIdx.x;    // 0..7
    const int bm   = blockIdx.y;    // 0..255
    const int m0   = bm * BM;
    const int n0   = bn * BN;
    const int col  = lane & 15;
    const int quad = lane >> 4;

    const bool has_spk = (flags[bm] != 0);

    f32x4 acc[4][2];
#pragma unroll
    for (int i = 0; i < 4; i++)
#pragma unroll
        for (int j = 0; j < 2; j++)
            acc[i][j] = (f32x4){0.f, 0.f, 0.f, 0.f};

    // ---- Phase 1: dense GEMM, K=256, bf16 ----
    for (int kb = 0; kb < DIN; kb += BK) {
        stageA(X,  DIN, m0, kb, tid, sA);
        stageB(Wd, DIN, n0, kb, tid, sB);
        __syncthreads();
#pragma unroll
        for (int ks = 0; ks < 2; ks++) {
            short8 ah[4], bh[2];
#pragma unroll
            for (int t = 0; t < 4; t++) {
                int ra = wm * 64 + t * 16 + col;
                ah[t] = *(const short8*)(sA + ra * 64 + (((ks * 4 + quad) ^ (ra & 7)) * 8));
            }
#pragma unroll
            for (int t = 0; t < 2; t++) {
                int rb = wn * 32 + t * 16 + col;
                bh[t] = *(const short8*)(sB + rb * 64 + (((ks * 4 + quad) ^ (rb & 7)) * 8));
            }
#pragma unroll
            for (int i = 0; i < 4; i++)
#pragma unroll
                for (int j = 0; j < 2; j++)
                    acc[i][j] = __builtin_amdgcn_mfma_f32_16x16x32_bf16(ah[i], bh[j], acc[i][j], 0, 0, 0);
        }
        __syncthreads();
    }

    // ---- Phase 2: recurrent GEMM, K=512 — only for m-tiles with spikes ----
    if (has_spk) {
        for (int kb = 0; kb < DOUT; kb += BK) {
            stageA(SPK, DOUT, m0, kb, tid, sA);
            stageB(Wr,  DOUT, n0, kb, tid, sB);
            __syncthreads();
#pragma unroll
            for (int ks = 0; ks < 2; ks++) {
                short8 ah[4], bh[2];
#pragma unroll
                for (int t = 0; t < 4; t++) {
                    int ra = wm * 64 + t * 16 + col;
                    ah[t] = *(const short8*)(sA + ra * 64 + (((ks * 4 + quad) ^ (ra & 7)) * 8));
                }
#pragma unroll
                for (int t = 0; t < 2; t++) {
                    int rb = wn * 32 + t * 16 + col;
                    bh[t] = *(const short8*)(sB + rb * 64 + (((ks * 4 + quad) ^ (rb & 7)) * 8));
                }
#pragma unroll
                for (int i = 0; i < 4; i++)
#pragma unroll
                    for (int j = 0; j < 2; j++)
                        acc[i][j] = __builtin_amdgcn_mfma_f32_16x16x32_bf16(ah[i], bh[j], acc[i][j], 0, 0, 0);
            }
            __syncthreads();
        }
    }

    // ---- Epilogue: fused LIF. C/D layout: col=lane&15, row=(lane>>4)*4+reg --
#pragma unroll
    for (int j = 0; j < 2; j++) {
        int n = n0 + wn * 32 + j * 16 + col;
        float alpha = expf(-1.0f / tau[n]);
        float bsum  = bd[n] + br[n];
#pragma unroll
        for (int i = 0; i < 4; i++) {
            int mbase = m0 + wm * 64 + i * 16 + quad * 4;
#pragma unroll
            for (int rr = 0; rr < 4; rr++) {
                size_t idx = (size_t)(mbase + rr) * DOUT + n;
                float d       = acc[i][j][rr] + bsum;
                float spk     = has_spk ? SPK[idx] : 0.0f;
                float mem_new = MEM[idx] * alpha + (1.0f - alpha) * d - 0.5f * spk;
                out[idx] = mem_new;
                out[(size_t)BATCH * DOUT + idx] = (mem_new - 0.5f > 0.0f) ? 1.0f : 0.0f;
            }
        }
    }
}

extern "C" void kernel_launch(void* const* d_in, const int* in_sizes, int n_in,
                              void* d_out, int out_size, void* d_ws, size_t ws_size,
                              hipStream_t stream) {
    const float* X   = (const float*)d_in[0];
    const float* MEM = (const float*)d_in[1];
    const float* SPK = (const float*)d_in[2];
    const float* Wd  = (const float*)d_in[3];
    const float* bd  = (const float*)d_in[4];
    const float* Wr  = (const float*)d_in[5];
    const float* br  = (const float*)d_in[6];
    const float* tau = (const float*)d_in[7];
    int* flags = (int*)d_ws;                       // 256 ints

    spike_flag_kernel<<<BATCH / BM, 1024, 0, stream>>>(SPK, flags);

    dim3 grid(DOUT / BN, BATCH / BM);              // (8, 256) = 2048 blocks
    spike_rnn_lif_kernel<<<grid, 256, 0, stream>>>(X, MEM, SPK, Wd, bd, Wr, br, tau,
                                                   flags, (float*)d_out);
}

// Round 4
// 317.928 us; speedup vs baseline: 1.1559x; 1.0733x over previous
//
#include <hip/hip_runtime.h>
#include <math.h>

typedef short  short8  __attribute__((ext_vector_type(8)));
typedef short  short4v __attribute__((ext_vector_type(4)));
typedef float  f32x4   __attribute__((ext_vector_type(4)));

#define BATCH 32768
#define DIN   256
#define DOUT  512
#define BM    128
#define BN    64

// ws layout (bytes)
#define WS_FLAGS 0
#define WS_WD2   4096
#define WS_WR2   (4096 + 262144)            // 266240
#define WS_X2    (266240 + 524288)          // 790528
// total ~17.6 MB

// round-to-nearest-even fp32 -> bf16 bits
__device__ __forceinline__ short f2bf(float v) {
    unsigned u = __float_as_uint(v);
    u += 0x7fffu + ((u >> 16) & 1u);
    return (short)(u >> 16);
}

// ---------------------------------------------------------------------------
// Pre-kernel 1: per-128-row-tile spike presence flags (reads SPK once, 64 MB).
// ---------------------------------------------------------------------------
__global__ __launch_bounds__(1024) void spike_flag_kernel(
    const float* __restrict__ SPK, int* __restrict__ flags)
{
    __shared__ int s_any;
    if (threadIdx.x == 0) s_any = 0;
    __syncthreads();
    const float4* p = (const float4*)(SPK + (size_t)blockIdx.x * BM * DOUT);
    unsigned bits = 0;
#pragma unroll
    for (int i = 0; i < 16; i++) {
        float4 v = p[threadIdx.x + i * 1024];
        bits |= __float_as_uint(v.x) | __float_as_uint(v.y)
              | __float_as_uint(v.z) | __float_as_uint(v.w);
    }
    if (bits) s_any = 1;
    __syncthreads();
    if (threadIdx.x == 0) flags[blockIdx.x] = s_any;
}

// ---------------------------------------------------------------------------
// Pre-kernel 2: fp32 -> bf16 image (row-major, layout preserved).
// One float4 per thread.
// ---------------------------------------------------------------------------
__global__ __launch_bounds__(256) void cvt_bf16_kernel(
    const float* __restrict__ src, short* __restrict__ dst, int n4)
{
    int i = blockIdx.x * 256 + threadIdx.x;
    if (i >= n4) return;
    float4 v = ((const float4*)src)[i];
    ((short4v*)dst)[i] = (short4v){f2bf(v.x), f2bf(v.y), f2bf(v.z), f2bf(v.w)};
}

// ---------------------------------------------------------------------------
// Main kernel. Block = 128(m) x 64(n), 4 waves as 2x2 of 64x32 wave tiles.
// K-loop reads bf16 A/B frags DIRECTLY from global (pre-converted images):
// no LDS staging, no converts, no barriers -> waves fully independent.
// A/B frag layout (r1-r3 end-to-end verified): row = lane&15, k = quad*8+j.
// Epilogue transposes acc via LDS so MEM/out are float4-coalesced.
// ---------------------------------------------------------------------------
__global__ __launch_bounds__(256, 4) void spike_rnn_lif_kernel(
    const short* __restrict__ X2,   // bf16 [B, 256]
    const float* __restrict__ MEM,  // [B, 512]
    const float* __restrict__ SPK,  // [B, 512]
    const short* __restrict__ Wd2,  // bf16 [512, 256]
    const float* __restrict__ bd,   // [512]
    const short* __restrict__ Wr2,  // bf16 [512, 512]
    const float* __restrict__ br,   // [512]
    const float* __restrict__ tau,  // [512]
    const int*   __restrict__ flags,// [256]
    float* __restrict__ out)        // [2, B, 512]
{
    __shared__ float sT[64 * 68];   // 17.4 KB transpose buffer (stride 68)

    const int tid  = threadIdx.x;
    const int lane = tid & 63;
    const int w    = tid >> 6;
    const int wm   = w & 1;
    const int wn   = w >> 1;
    const int bn   = blockIdx.x;    // 0..7
    const int bm   = blockIdx.y;    // 0..255
    const int m0   = bm * BM;
    const int n0   = bn * BN;
    const int col  = lane & 15;
    const int quad = lane >> 4;

    const bool has_spk = (flags[bm] != 0);

    f32x4 acc[4][2];
#pragma unroll
    for (int i = 0; i < 4; i++)
#pragma unroll
        for (int j = 0; j < 2; j++)
            acc[i][j] = (f32x4){0.f, 0.f, 0.f, 0.f};

    // ---- Phase 1: dense GEMM, K=256, barrier-free ----
    {
        const short* Abase = X2  + (size_t)(m0 + wm * 64 + col) * DIN + quad * 8;
        const short* Bbase = Wd2 + (size_t)(n0 + wn * 32 + col) * DIN + quad * 8;
#pragma unroll
        for (int ks = 0; ks < 8; ks++) {
            int k = ks * 32;
            short8 a[4], b[2];
#pragma unroll
            for (int t = 0; t < 4; t++)
                a[t] = *(const short8*)(Abase + (size_t)t * 16 * DIN + k);
#pragma unroll
            for (int t = 0; t < 2; t++)
                b[t] = *(const short8*)(Bbase + (size_t)t * 16 * DIN + k);
#pragma unroll
            for (int i = 0; i < 4; i++)
#pragma unroll
                for (int j = 0; j < 2; j++)
                    acc[i][j] = __builtin_amdgcn_mfma_f32_16x16x32_bf16(a[i], b[j], acc[i][j], 0, 0, 0);
        }
    }

    // ---- Phase 2: recurrent GEMM, K=512 — only when spikes exist.
    //      A = SPK fp32 (in-register convert), B = Wr bf16 image. Barrier-free.
    if (has_spk) {
        const float* Abase = SPK + (size_t)(m0 + wm * 64 + col) * DOUT + quad * 8;
        const short* Bbase = Wr2 + (size_t)(n0 + wn * 32 + col) * DOUT + quad * 8;
#pragma unroll 4
        for (int ks = 0; ks < 16; ks++) {
            int k = ks * 32;
            short8 a[4], b[2];
#pragma unroll
            for (int t = 0; t < 4; t++) {
                const float* ap = Abase + (size_t)t * 16 * DOUT + k;
                float4 lo = *(const float4*)ap;
                float4 hi = *(const float4*)(ap + 4);
                a[t] = (short8){f2bf(lo.x), f2bf(lo.y), f2bf(lo.z), f2bf(lo.w),
                                f2bf(hi.x), f2bf(hi.y), f2bf(hi.z), f2bf(hi.w)};
            }
#pragma unroll
            for (int t = 0; t < 2; t++)
                b[t] = *(const short8*)(Bbase + (size_t)t * 16 * DOUT + k);
#pragma unroll
            for (int i = 0; i < 4; i++)
#pragma unroll
                for (int j = 0; j < 2; j++)
                    acc[i][j] = __builtin_amdgcn_mfma_f32_16x16x32_bf16(a[i], b[j], acc[i][j], 0, 0, 0);
        }
    }

    // ---- Epilogue: transpose via LDS, then fully-vectorized LIF ----
    // Per-thread fixed columns: n = n0 + (tid&15)*4 + 0..3
    const int c4   = tid & 15;
    const int ncol = n0 + c4 * 4;
    float al[4], oma[4], bs[4];
#pragma unroll
    for (int q = 0; q < 4; q++) {
        al[q]  = expf(-1.0f / tau[ncol + q]);
        oma[q] = 1.0f - al[q];
        bs[q]  = bd[ncol + q] + br[ncol + q];
    }

#pragma unroll
    for (int c = 0; c < 2; c++) {            // two 64-row chunks
        if (c) __syncthreads();              // prior chunk's readers done
        if (wm == c) {
            // C/D layout (verified): col = lane&15, row = quad*4 + reg
#pragma unroll
            for (int j = 0; j < 2; j++)
#pragma unroll
                for (int i = 0; i < 4; i++)
#pragma unroll
                    for (int rr = 0; rr < 4; rr++)
                        sT[(i * 16 + quad * 4 + rr) * 68 + wn * 32 + j * 16 + col]
                            = acc[i][j][rr];
        }
        __syncthreads();
#pragma unroll
        for (int it = 0; it < 4; it++) {
            int p   = tid + it * 256;
            int r2  = p >> 4;                 // 0..63
            int row = m0 + c * 64 + r2;
            f32x4  d   = *(const f32x4*)(sT + r2 * 68 + c4 * 4);
            float4 mv  = *(const float4*)(MEM + (size_t)row * DOUT + ncol);
            float4 sv  = has_spk ? *(const float4*)(SPK + (size_t)row * DOUT + ncol)
                                 : (float4){0.f, 0.f, 0.f, 0.f};
            float4 mn, sp;
            mn.x = mv.x * al[0] + oma[0] * (d[0] + bs[0]) - 0.5f * sv.x;
            mn.y = mv.y * al[1] + oma[1] * (d[1] + bs[1]) - 0.5f * sv.y;
            mn.z = mv.z * al[2] + oma[2] * (d[2] + bs[2]) - 0.5f * sv.z;
            mn.w = mv.w * al[3] + oma[3] * (d[3] + bs[3]) - 0.5f * sv.w;
            sp.x = (mn.x - 0.5f > 0.0f) ? 1.0f : 0.0f;
            sp.y = (mn.y - 0.5f > 0.0f) ? 1.0f : 0.0f;
            sp.z = (mn.z - 0.5f > 0.0f) ? 1.0f : 0.0f;
            sp.w = (mn.w - 0.5f > 0.0f) ? 1.0f : 0.0f;
            *(float4*)(out + (size_t)row * DOUT + ncol) = mn;
            *(float4*)(out + (size_t)BATCH * DOUT + (size_t)row * DOUT + ncol) = sp;
        }
    }
}

extern "C" void kernel_launch(void* const* d_in, const int* in_sizes, int n_in,
                              void* d_out, int out_size, void* d_ws, size_t ws_size,
                              hipStream_t stream) {
    const float* X   = (const float*)d_in[0];
    const float* MEM = (const float*)d_in[1];
    const float* SPK = (const float*)d_in[2];
    const float* Wd  = (const float*)d_in[3];
    const float* bd  = (const float*)d_in[4];
    const float* Wr  = (const float*)d_in[5];
    const float* br  = (const float*)d_in[6];
    const float* tau = (const float*)d_in[7];

    char*  ws    = (char*)d_ws;
    int*   flags = (int*)  (ws + WS_FLAGS);
    short* Wd2   = (short*)(ws + WS_WD2);
    short* Wr2   = (short*)(ws + WS_WR2);
    short* X2    = (short*)(ws + WS_X2);

    // Pre-pass: flags + bf16 images
    spike_flag_kernel<<<BATCH / BM, 1024, 0, stream>>>(SPK, flags);
    {
        int n4 = DOUT * DIN / 4;     // Wd: 32768 float4
        cvt_bf16_kernel<<<(n4 + 255) / 256, 256, 0, stream>>>(Wd, Wd2, n4);
    }
    {
        int n4 = DOUT * DOUT / 4;    // Wr: 65536 float4
        cvt_bf16_kernel<<<(n4 + 255) / 256, 256, 0, stream>>>(Wr, Wr2, n4);
    }
    {
        int n4 = BATCH * DIN / 4;    // X: 2M float4
        cvt_bf16_kernel<<<(n4 + 255) / 256, 256, 0, stream>>>(X, X2, n4);
    }

    dim3 grid(DOUT / BN, BATCH / BM);          // (8, 256) = 2048 blocks
    spike_rnn_lif_kernel<<<grid, 256, 0, stream>>>(X2, MEM, SPK, Wd2, bd, Wr2, br,
                                                   tau, flags, (float*)d_out);
}

// Round 6
// 311.411 us; speedup vs baseline: 1.1801x; 1.0209x over previous
//
#include <hip/hip_runtime.h>
#include <math.h>

typedef short  short8  __attribute__((ext_vector_type(8)));
typedef short  short4v __attribute__((ext_vector_type(4)));
typedef float  f32x4   __attribute__((ext_vector_type(4)));

#define BATCH 32768
#define DIN   256
#define DOUT  512
#define BM    128
#define BN    64

// ws layout (bytes)
#define WS_FLAGS 0
#define WS_WD2   4096
#define WS_WR2   (4096 + 262144)
#define WS_X2    (266240 + 524288)

// round-to-nearest-even fp32 -> bf16 bits
__device__ __forceinline__ short f2bf(float v) {
    unsigned u = __float_as_uint(v);
    u += 0x7fffu + ((u >> 16) & 1u);
    return (short)(u >> 16);
}

// ---------------------------------------------------------------------------
// Pre-kernel 1: per-128-row-tile spike presence flags (reads SPK once, 64 MB).
// ---------------------------------------------------------------------------
__global__ __launch_bounds__(1024) void spike_flag_kernel(
    const float* __restrict__ SPK, int* __restrict__ flags)
{
    __shared__ int s_any;
    if (threadIdx.x == 0) s_any = 0;
    __syncthreads();
    const f32x4* p = (const f32x4*)(SPK + (size_t)blockIdx.x * BM * DOUT);
    unsigned bits = 0;
#pragma unroll
    for (int i = 0; i < 16; i++) {
        f32x4 v = p[threadIdx.x + i * 1024];
        bits |= __float_as_uint(v[0]) | __float_as_uint(v[1])
              | __float_as_uint(v[2]) | __float_as_uint(v[3]);
    }
    if (bits) s_any = 1;
    __syncthreads();
    if (threadIdx.x == 0) flags[blockIdx.x] = s_any;
}

// ---------------------------------------------------------------------------
// Pre-kernel 2: fp32 -> bf16 image (row-major, layout preserved).
// ---------------------------------------------------------------------------
__global__ __launch_bounds__(256) void cvt_bf16_kernel(
    const float* __restrict__ src, short* __restrict__ dst, int n4)
{
    int i = blockIdx.x * 256 + threadIdx.x;
    if (i >= n4) return;
    f32x4 v = ((const f32x4*)src)[i];
    ((short4v*)dst)[i] = (short4v){f2bf(v[0]), f2bf(v[1]), f2bf(v[2]), f2bf(v[3])};
}

// ---------------------------------------------------------------------------
// Main kernel. Block = 128(m) x 64(n), 4 waves as 2x2 of 64x32 wave tiles.
// r4 was latency-bound at ~0.3 outstanding loads/wave (VGPR=56: compiler
// recycled load regs -> serialized). r5: register double-buffered K-loop +
// epilogue MEM prefetched into regs at the head -> ~6-10 loads in flight per
// wave. launch_bounds(256,3) gives the allocator the ~140-reg budget.
// ---------------------------------------------------------------------------
__global__ __launch_bounds__(256, 3) void spike_rnn_lif_kernel(
    const short* __restrict__ X2,   // bf16 [B, 256]
    const float* __restrict__ MEM,  // [B, 512]
    const float* __restrict__ SPK,  // [B, 512]
    const short* __restrict__ Wd2,  // bf16 [512, 256]
    const float* __restrict__ bd,   // [512]
    const short* __restrict__ Wr2,  // bf16 [512, 512]
    const float* __restrict__ br,   // [512]
    const float* __restrict__ tau,  // [512]
    const int*   __restrict__ flags,// [256]
    float* __restrict__ out)        // [2, B, 512]
{
    __shared__ float sT[64 * 68];   // 17.4 KB transpose buffer

    const int tid  = threadIdx.x;
    const int lane = tid & 63;
    const int w    = tid >> 6;
    const int wm   = w & 1;
    const int wn   = w >> 1;
    const int bn   = blockIdx.x;    // 0..7
    const int bm   = blockIdx.y;    // 0..255
    const int m0   = bm * BM;
    const int n0   = bn * BN;
    const int col  = lane & 15;
    const int quad = lane >> 4;

    const bool has_spk = (flags[bm] != 0);

    // ---- Epilogue prefetch, chunk 0: 4 float4 of MEM in flight during GEMM
    const int c4   = tid & 15;
    const int ncol = n0 + c4 * 4;
    f32x4 mv0[4];
#pragma unroll
    for (int it = 0; it < 4; it++) {
        int row = m0 + ((tid + it * 256) >> 4);
        mv0[it] = __builtin_nontemporal_load(
                      (const f32x4*)(MEM + (size_t)row * DOUT + ncol));
    }

    f32x4 acc[4][2];
#pragma unroll
    for (int i = 0; i < 4; i++)
#pragma unroll
        for (int j = 0; j < 2; j++)
            acc[i][j] = (f32x4){0.f, 0.f, 0.f, 0.f};

    // ---- Phase 1: dense GEMM, K=256, barrier-free, 2-deep reg pipeline ----
    {
        const short* Abase = X2  + (size_t)(m0 + wm * 64 + col) * DIN + quad * 8;
        const short* Bbase = Wd2 + (size_t)(n0 + wn * 32 + col) * DIN + quad * 8;

#define LOAD_AB(kk, aa, bb)                                                   \
        do {                                                                  \
            int k_ = (kk) * 32;                                               \
            _Pragma("unroll")                                                 \
            for (int t = 0; t < 4; t++)                                       \
                aa[t] = *(const short8*)(Abase + (size_t)t * 16 * DIN + k_);  \
            _Pragma("unroll")                                                 \
            for (int t = 0; t < 2; t++)                                       \
                bb[t] = *(const short8*)(Bbase + (size_t)t * 16 * DIN + k_);  \
        } while (0)

#define MFMA_AB(aa, bb)                                                       \
        do {                                                                  \
            _Pragma("unroll")                                                 \
            for (int i = 0; i < 4; i++)                                       \
                _Pragma("unroll")                                             \
                for (int j = 0; j < 2; j++)                                   \
                    acc[i][j] = __builtin_amdgcn_mfma_f32_16x16x32_bf16(      \
                        aa[i], bb[j], acc[i][j], 0, 0, 0);                    \
        } while (0)

        short8 a0[4], b0[2], a1[4], b1[2];
        LOAD_AB(0, a0, b0);
#pragma unroll
        for (int kp = 0; kp < 4; kp++) {
            LOAD_AB(2 * kp + 1, a1, b1);
            MFMA_AB(a0, b0);
            if (kp < 3) LOAD_AB(2 * kp + 2, a0, b0);
            MFMA_AB(a1, b1);
        }
#undef LOAD_AB
    }

    // ---- Phase 2: recurrent GEMM, K=512 — only when spikes exist ----
    if (has_spk) {
        const float* Abase = SPK + (size_t)(m0 + wm * 64 + col) * DOUT + quad * 8;
        const short* Bbase = Wr2 + (size_t)(n0 + wn * 32 + col) * DOUT + quad * 8;
#pragma unroll 4
        for (int ks = 0; ks < 16; ks++) {
            int k = ks * 32;
            short8 a[4], b[2];
#pragma unroll
            for (int t = 0; t < 4; t++) {
                const float* ap = Abase + (size_t)t * 16 * DOUT + k;
                f32x4 lo = *(const f32x4*)ap;
                f32x4 hi = *(const f32x4*)(ap + 4);
                a[t] = (short8){f2bf(lo[0]), f2bf(lo[1]), f2bf(lo[2]), f2bf(lo[3]),
                                f2bf(hi[0]), f2bf(hi[1]), f2bf(hi[2]), f2bf(hi[3])};
            }
#pragma unroll
            for (int t = 0; t < 2; t++)
                b[t] = *(const short8*)(Bbase + (size_t)t * 16 * DOUT + k);
            MFMA_AB(a, b);
        }
    }
#undef MFMA_AB

    // ---- Epilogue prefetch, chunk 1 (hidden behind chunk-0 epilogue) ----
    f32x4 mv1[4];
#pragma unroll
    for (int it = 0; it < 4; it++) {
        int row = m0 + 64 + ((tid + it * 256) >> 4);
        mv1[it] = __builtin_nontemporal_load(
                      (const f32x4*)(MEM + (size_t)row * DOUT + ncol));
    }

    float al[4], oma[4], bs[4];
#pragma unroll
    for (int q = 0; q < 4; q++) {
        al[q]  = expf(-1.0f / tau[ncol + q]);
        oma[q] = 1.0f - al[q];
        bs[q]  = bd[ncol + q] + br[ncol + q];
    }

#pragma unroll
    for (int c = 0; c < 2; c++) {
        if (c) __syncthreads();
        if (wm == c) {
            // C/D layout (verified): col = lane&15, row = quad*4 + reg
#pragma unroll
            for (int j = 0; j < 2; j++)
#pragma unroll
                for (int i = 0; i < 4; i++)
#pragma unroll
                    for (int rr = 0; rr < 4; rr++)
                        sT[(i * 16 + quad * 4 + rr) * 68 + wn * 32 + j * 16 + col]
                            = acc[i][j][rr];
        }
        __syncthreads();
#pragma unroll
        for (int it = 0; it < 4; it++) {
            int p   = tid + it * 256;
            int r2  = p >> 4;
            int row = m0 + c * 64 + r2;
            f32x4 d  = *(const f32x4*)(sT + r2 * 68 + c4 * 4);
            f32x4 mv = c ? mv1[it] : mv0[it];
            f32x4 sv = has_spk ? *(const f32x4*)(SPK + (size_t)row * DOUT + ncol)
                               : (f32x4){0.f, 0.f, 0.f, 0.f};
            f32x4 mn, sp;
#pragma unroll
            for (int q = 0; q < 4; q++) {
                mn[q] = mv[q] * al[q] + oma[q] * (d[q] + bs[q]) - 0.5f * sv[q];
                sp[q] = (mn[q] - 0.5f > 0.0f) ? 1.0f : 0.0f;
            }
            __builtin_nontemporal_store(mn,
                (f32x4*)(out + (size_t)row * DOUT + ncol));
            __builtin_nontemporal_store(sp,
                (f32x4*)(out + (size_t)BATCH * DOUT + (size_t)row * DOUT + ncol));
        }
    }
}

extern "C" void kernel_launch(void* const* d_in, const int* in_sizes, int n_in,
                              void* d_out, int out_size, void* d_ws, size_t ws_size,
                              hipStream_t stream) {
    const float* X   = (const float*)d_in[0];
    const float* MEM = (const float*)d_in[1];
    const float* SPK = (const float*)d_in[2];
    const float* Wd  = (const float*)d_in[3];
    const float* bd  = (const float*)d_in[4];
    const float* Wr  = (const float*)d_in[5];
    const float* br  = (const float*)d_in[6];
    const float* tau = (const float*)d_in[7];

    char*  ws    = (char*)d_ws;
    int*   flags = (int*)  (ws + WS_FLAGS);
    short* Wd2   = (short*)(ws + WS_WD2);
    short* Wr2   = (short*)(ws + WS_WR2);
    short* X2    = (short*)(ws + WS_X2);

    spike_flag_kernel<<<BATCH / BM, 1024, 0, stream>>>(SPK, flags);
    {
        int n4 = DOUT * DIN / 4;
        cvt_bf16_kernel<<<(n4 + 255) / 256, 256, 0, stream>>>(Wd, Wd2, n4);
    }
    {
        int n4 = DOUT * DOUT / 4;
        cvt_bf16_kernel<<<(n4 + 255) / 256, 256, 0, stream>>>(Wr, Wr2, n4);
    }
    {
        int n4 = BATCH * DIN / 4;
        cvt_bf16_kernel<<<(n4 + 255) / 256, 256, 0, stream>>>(X, X2, n4);
    }

    dim3 grid(DOUT / BN, BATCH / BM);          // (8, 256) = 2048 blocks
    spike_rnn_lif_kernel<<<grid, 256, 0, stream>>>(X2, MEM, SPK, Wd2, bd, Wr2, br,
                                                   tau, flags, (float*)d_out);
}

// Round 7
// 304.599 us; speedup vs baseline: 1.2065x; 1.0224x over previous
//
#include <hip/hip_runtime.h>
#include <math.h>

typedef short  short8  __attribute__((ext_vector_type(8)));
typedef short  short4v __attribute__((ext_vector_type(4)));
typedef float  f32x4   __attribute__((ext_vector_type(4)));

#define BATCH 32768
#define DIN   256
#define DOUT  512
#define BM    128
#define BN    64

// ws layout (bytes)
#define WS_FLAGS 0
#define WS_WD2   4096
#define WS_WR2   (4096 + 262144)
#define WS_X2    (266240 + 524288)

// round-to-nearest-even fp32 -> bf16 bits
__device__ __forceinline__ short f2bf(float v) {
    unsigned u = __float_as_uint(v);
    u += 0x7fffu + ((u >> 16) & 1u);
    return (short)(u >> 16);
}

// ---------------------------------------------------------------------------
// Fused pre-pass (one launch, 2048 blocks x 256):
//   A) SPK flag scan (64 MB) -> atomicOr into flags[bm]
//   B) X fp32 -> bf16 (50 MB)
//   C) Wd+Wr fp32 -> bf16 (4.5 MB)
// r6 ran these as 4 launches ~42 us; fused streaming ~20 us.
// ---------------------------------------------------------------------------
__global__ __launch_bounds__(256) void prepass_kernel(
    const float* __restrict__ SPK, const float* __restrict__ X,
    const float* __restrict__ Wd,  const float* __restrict__ Wr,
    int* __restrict__ flags, short* __restrict__ X2,
    short* __restrict__ Wd2, short* __restrict__ Wr2)
{
    const int b   = blockIdx.x;      // 0..2047
    const int tid = threadIdx.x;

    // A) flag scan: block b covers float4 [b*2048, b*2048+2048) = 16 SPK rows
    {
        unsigned bits = 0;
        const f32x4* p = (const f32x4*)SPK + (size_t)b * 2048;
#pragma unroll
        for (int j = 0; j < 8; j++) {
            f32x4 v = p[tid + j * 256];
            bits |= __float_as_uint(v[0]) | __float_as_uint(v[1])
                  | __float_as_uint(v[2]) | __float_as_uint(v[3]);
        }
        if (__any(bits != 0) && (tid & 63) == 0)
            atomicOr(&flags[b >> 3], 1);
    }

    // B) X convert: block b covers float4 [b*1024, b*1024+1024)
    {
        const f32x4* src = (const f32x4*)X + (size_t)b * 1024;
        short4v*     dst = (short4v*)X2   + (size_t)b * 1024;
#pragma unroll
        for (int j = 0; j < 4; j++) {
            f32x4 v = src[tid + j * 256];
            dst[tid + j * 256] = (short4v){f2bf(v[0]), f2bf(v[1]),
                                           f2bf(v[2]), f2bf(v[3])};
        }
    }

    // C) weights: 32768 f4 (Wd) + 65536 f4 (Wr), first 98304 threads
    {
        int idx = b * 256 + tid;
        if (idx < 32768) {
            f32x4 v = ((const f32x4*)Wd)[idx];
            ((short4v*)Wd2)[idx] = (short4v){f2bf(v[0]), f2bf(v[1]),
                                             f2bf(v[2]), f2bf(v[3])};
        } else if (idx < 98304) {
            int k = idx - 32768;
            f32x4 v = ((const f32x4*)Wr)[k];
            ((short4v*)Wr2)[k] = (short4v){f2bf(v[0]), f2bf(v[1]),
                                           f2bf(v[2]), f2bf(v[3])};
        }
    }
}

// ---------------------------------------------------------------------------
// Main kernel. Block = 128(m) x 64(n), 4 waves as 2x2 of 64x32 wave tiles.
// 1-D grid with XCD swizzle: L = bmhi*64 + bn*8 + (bm&7), so the 8 bn-blocks
// sharing one X2 m-slice are consecutive dispatches on ONE XCD (L%8 = bm%8)
// -> X2 re-reads hit that XCD's L2 (~200 cyc) instead of L3 (~600+).
// Per-XCD X2 compulsory = 32 slices x 64 KB = 2 MB (L2-resident).
// ---------------------------------------------------------------------------
__global__ __launch_bounds__(256, 3) void spike_rnn_lif_kernel(
    const short* __restrict__ X2,   // bf16 [B, 256]
    const float* __restrict__ MEM,  // [B, 512]
    const float* __restrict__ SPK,  // [B, 512]
    const short* __restrict__ Wd2,  // bf16 [512, 256]
    const float* __restrict__ bd,   // [512]
    const short* __restrict__ Wr2,  // bf16 [512, 512]
    const float* __restrict__ br,   // [512]
    const float* __restrict__ tau,  // [512]
    const int*   __restrict__ flags,// [256]
    float* __restrict__ out)        // [2, B, 512]
{
    __shared__ float sT[64 * 68];   // 17.4 KB transpose buffer

    const int tid  = threadIdx.x;
    const int lane = tid & 63;
    const int w    = tid >> 6;
    const int wm   = w & 1;
    const int wn   = w >> 1;

    // XCD swizzle decode (bijective): L = ((bm/8)*8 + bn)*8 + bm%8
    const int L    = blockIdx.x;
    const int bm   = ((L >> 6) << 3) + (L & 7);
    const int bn   = (L >> 3) & 7;
    const int m0   = bm * BM;
    const int n0   = bn * BN;
    const int col  = lane & 15;
    const int quad = lane >> 4;

    const bool has_spk = (flags[bm] != 0);

    // ---- Epilogue prefetch: BOTH 64-row chunks of MEM in flight during GEMM
    const int c4   = tid & 15;
    const int ncol = n0 + c4 * 4;
    f32x4 mv0[4], mv1[4];
#pragma unroll
    for (int it = 0; it < 4; it++) {
        int r2 = (tid + it * 256) >> 4;
        mv0[it] = __builtin_nontemporal_load(
                      (const f32x4*)(MEM + (size_t)(m0 + r2) * DOUT + ncol));
        mv1[it] = __builtin_nontemporal_load(
                      (const f32x4*)(MEM + (size_t)(m0 + 64 + r2) * DOUT + ncol));
    }

    f32x4 acc[4][2];
#pragma unroll
    for (int i = 0; i < 4; i++)
#pragma unroll
        for (int j = 0; j < 2; j++)
            acc[i][j] = (f32x4){0.f, 0.f, 0.f, 0.f};

    // ---- Phase 1: dense GEMM, K=256, barrier-free, 2-deep reg pipeline ----
    {
        const short* Abase = X2  + (size_t)(m0 + wm * 64 + col) * DIN + quad * 8;
        const short* Bbase = Wd2 + (size_t)(n0 + wn * 32 + col) * DIN + quad * 8;

#define LOAD_AB(kk, aa, bb)                                                   \
        do {                                                                  \
            int k_ = (kk) * 32;                                               \
            _Pragma("unroll")                                                 \
            for (int t = 0; t < 4; t++)                                       \
                aa[t] = *(const short8*)(Abase + (size_t)t * 16 * DIN + k_);  \
            _Pragma("unroll")                                                 \
            for (int t = 0; t < 2; t++)                                       \
                bb[t] = *(const short8*)(Bbase + (size_t)t * 16 * DIN + k_);  \
        } while (0)

#define MFMA_AB(aa, bb)                                                       \
        do {                                                                  \
            _Pragma("unroll")                                                 \
            for (int i = 0; i < 4; i++)                                       \
                _Pragma("unroll")                                             \
                for (int j = 0; j < 2; j++)                                   \
                    acc[i][j] = __builtin_amdgcn_mfma_f32_16x16x32_bf16(      \
                        aa[i], bb[j], acc[i][j], 0, 0, 0);                    \
        } while (0)

        short8 a0[4], b0[2], a1[4], b1[2];
        LOAD_AB(0, a0, b0);
#pragma unroll
        for (int kp = 0; kp < 4; kp++) {
            LOAD_AB(2 * kp + 1, a1, b1);
            MFMA_AB(a0, b0);
            if (kp < 3) LOAD_AB(2 * kp + 2, a0, b0);
            MFMA_AB(a1, b1);
        }
#undef LOAD_AB
    }

    // ---- Phase 2: recurrent GEMM, K=512 — only when spikes exist ----
    if (has_spk) {
        const float* Abase = SPK + (size_t)(m0 + wm * 64 + col) * DOUT + quad * 8;
        const short* Bbase = Wr2 + (size_t)(n0 + wn * 32 + col) * DOUT + quad * 8;
#pragma unroll 4
        for (int ks = 0; ks < 16; ks++) {
            int k = ks * 32;
            short8 a[4], b[2];
#pragma unroll
            for (int t = 0; t < 4; t++) {
                const float* ap = Abase + (size_t)t * 16 * DOUT + k;
                f32x4 lo = *(const f32x4*)ap;
                f32x4 hi = *(const f32x4*)(ap + 4);
                a[t] = (short8){f2bf(lo[0]), f2bf(lo[1]), f2bf(lo[2]), f2bf(lo[3]),
                                f2bf(hi[0]), f2bf(hi[1]), f2bf(hi[2]), f2bf(hi[3])};
            }
#pragma unroll
            for (int t = 0; t < 2; t++)
                b[t] = *(const short8*)(Bbase + (size_t)t * 16 * DOUT + k);
            MFMA_AB(a, b);
        }
    }
#undef MFMA_AB

    float al[4], oma[4], bs[4];
#pragma unroll
    for (int q = 0; q < 4; q++) {
        al[q]  = expf(-1.0f / tau[ncol + q]);
        oma[q] = 1.0f - al[q];
        bs[q]  = bd[ncol + q] + br[ncol + q];
    }

#pragma unroll
    for (int c = 0; c < 2; c++) {
        if (c) __syncthreads();
        if (wm == c) {
            // C/D layout (verified): col = lane&15, row = quad*4 + reg
#pragma unroll
            for (int j = 0; j < 2; j++)
#pragma unroll
                for (int i = 0; i < 4; i++)
#pragma unroll
                    for (int rr = 0; rr < 4; rr++)
                        sT[(i * 16 + quad * 4 + rr) * 68 + wn * 32 + j * 16 + col]
                            = acc[i][j][rr];
        }
        __syncthreads();
#pragma unroll
        for (int it = 0; it < 4; it++) {
            int p   = tid + it * 256;
            int r2  = p >> 4;
            int row = m0 + c * 64 + r2;
            f32x4 d  = *(const f32x4*)(sT + r2 * 68 + c4 * 4);
            f32x4 mv = c ? mv1[it] : mv0[it];
            f32x4 sv = has_spk ? *(const f32x4*)(SPK + (size_t)row * DOUT + ncol)
                               : (f32x4){0.f, 0.f, 0.f, 0.f};
            f32x4 mn, sp;
#pragma unroll
            for (int q = 0; q < 4; q++) {
                mn[q] = mv[q] * al[q] + oma[q] * (d[q] + bs[q]) - 0.5f * sv[q];
                sp[q] = (mn[q] - 0.5f > 0.0f) ? 1.0f : 0.0f;
            }
            __builtin_nontemporal_store(mn,
                (f32x4*)(out + (size_t)row * DOUT + ncol));
            __builtin_nontemporal_store(sp,
                (f32x4*)(out + (size_t)BATCH * DOUT + (size_t)row * DOUT + ncol));
        }
    }
}

extern "C" void kernel_launch(void* const* d_in, const int* in_sizes, int n_in,
                              void* d_out, int out_size, void* d_ws, size_t ws_size,
                              hipStream_t stream) {
    const float* X   = (const float*)d_in[0];
    const float* MEM = (const float*)d_in[1];
    const float* SPK = (const float*)d_in[2];
    const float* Wd  = (const float*)d_in[3];
    const float* bd  = (const float*)d_in[4];
    const float* Wr  = (const float*)d_in[5];
    const float* br  = (const float*)d_in[6];
    const float* tau = (const float*)d_in[7];

    char*  ws    = (char*)d_ws;
    int*   flags = (int*)  (ws + WS_FLAGS);
    short* Wd2   = (short*)(ws + WS_WD2);
    short* Wr2   = (short*)(ws + WS_WR2);
    short* X2    = (short*)(ws + WS_X2);

    hipMemsetAsync(flags, 0, 256 * sizeof(int), stream);   // graph-capture-safe
    prepass_kernel<<<2048, 256, 0, stream>>>(SPK, X, Wd, Wr, flags, X2, Wd2, Wr2);

    spike_rnn_lif_kernel<<<2048, 256, 0, stream>>>(X2, MEM, SPK, Wd2, bd, Wr2, br,
                                                   tau, flags, (float*)d_out);
}